// Round 1
// baseline (490.778 us; speedup 1.0000x reference)
//
#include <hip/hip_runtime.h>
#include <cstdint>
#include <cstddef>

// ---- problem constants ----
#define EMB   1024
#define NH    16
#define HD    64
#define SEQ   2048
#define NB    4
#define MROWS 8192   // NB*SEQ

typedef short short8 __attribute__((ext_vector_type(8)));
typedef float floatx4 __attribute__((ext_vector_type(4)));

__device__ __forceinline__ unsigned short f2bf(float f) {
  unsigned int u = __float_as_uint(f);
  u = u + 0x7fffu + ((u >> 16) & 1u);
  return (unsigned short)(u >> 16);
}

// ---------------- time weights: softmax(time_enc @ Wt + bt) * (1/sqrt(D)) ----------------
__global__ void time_weights_kernel(const float* __restrict__ te, const float* __restrict__ Wt,
                                    const float* __restrict__ bt, float* __restrict__ tw) {
  int t = threadIdx.x;           // 64 threads = 1 wave; t = b*16 + h
  int b = t >> 4, h = t & 15;
  float acc = bt[h];
  for (int i = 0; i < 128; i++) acc += te[b * 128 + i] * Wt[i * 16 + h];
  float m = acc;
  for (int off = 1; off < 16; off <<= 1) m = fmaxf(m, __shfl_xor(m, off, 16));
  float e = __expf(acc - m);
  float s = e;
  for (int off = 1; off < 16; off <<= 1) s += __shfl_xor(s, off, 16);
  tw[t] = (e / s) * 0.125f;      // fold in 1/sqrt(64)
}

// ---------------- x (fp32) -> bf16 ----------------
__global__ void convert_x_kernel(const float4* __restrict__ x, unsigned short* __restrict__ out) {
  int i = blockIdx.x * blockDim.x + threadIdx.x;   // exactly 2097152 threads
  float4 v = x[i];
  union { unsigned short u[4]; uint2 p; } o;
  o.u[0] = f2bf(v.x); o.u[1] = f2bf(v.y); o.u[2] = f2bf(v.z); o.u[3] = f2bf(v.w);
  *(uint2*)&out[(size_t)i * 4] = o.p;
}

// ---------------- W [K][N] fp32 -> W^T [N][K] bf16 (tiled transpose) ----------------
__global__ void transpose_convert_kernel(const float* __restrict__ W, unsigned short* __restrict__ out) {
  __shared__ float tile[32][33];
  int k0 = blockIdx.x * 32;
  int n0 = blockIdx.y * 32;
  int tx = threadIdx.x;   // 0..31
  int ty = threadIdx.y;   // 0..7
#pragma unroll
  for (int i = 0; i < 4; i++) {
    int k = ty + i * 8;
    tile[k][tx] = W[(size_t)(k0 + k) * EMB + n0 + tx];
  }
  __syncthreads();
#pragma unroll
  for (int i = 0; i < 4; i++) {
    int n = ty + i * 8;
    out[(size_t)(n0 + n) * EMB + k0 + tx] = f2bf(tile[tx][n]);
  }
}

// ---------------- GEMM: C[M][N] = A[M][K=1024] @ Bt[N][K=1024]^T ----------------
// 128x128 block tile, BK=32, 4 waves (2x2), each wave 64x64 via 4x4 MFMA 16x16x32 tiles.
// EPI==0: scatter to q[b,h,s,d], k[b,h,s,d], vt[b,h,d,s] (bf16).  N=3072.
// EPI==1: out fp32 = acc + bias[n].  N=1024.
template <int EPI>
__global__ __launch_bounds__(256) void gemm_kernel(
    const unsigned short* __restrict__ A, const unsigned short* __restrict__ Bt,
    unsigned short* __restrict__ qo, unsigned short* __restrict__ ko, unsigned short* __restrict__ vto,
    float* __restrict__ outf, const float* __restrict__ bias) {
  __shared__ unsigned short As[128 * 40];   // +8 pad: row stride 80 B (16B-aligned, 2-way banks)
  __shared__ unsigned short Bs[128 * 40];

  int tid = threadIdx.x;
  int lane = tid & 63, wid = tid >> 6;
  int quad = lane >> 4, l16 = lane & 15;
  int wm = wid >> 1, wn = wid & 1;
  int m0 = blockIdx.y * 128, n0 = blockIdx.x * 128;

  floatx4 acc[4][4];
#pragma unroll
  for (int mi = 0; mi < 4; mi++)
#pragma unroll
    for (int ni = 0; ni < 4; ni++)
#pragma unroll
      for (int r = 0; r < 4; r++) acc[mi][ni][r] = 0.f;

  for (int k0 = 0; k0 < 1024; k0 += 32) {
    // stage 128x32 tiles of A and Bt
#pragma unroll
    for (int c = 0; c < 2; c++) {
      int flat = c * 2048 + tid * 8;
      int r = flat >> 5, col = flat & 31;
      *(uint4*)&As[r * 40 + col] = *(const uint4*)&A[(size_t)(m0 + r) * 1024 + k0 + col];
      *(uint4*)&Bs[r * 40 + col] = *(const uint4*)&Bt[(size_t)(n0 + r) * 1024 + k0 + col];
    }
    __syncthreads();

    short8 a_frag[4], b_frag[4];
#pragma unroll
    for (int mi = 0; mi < 4; mi++)
      a_frag[mi] = *(const short8*)&As[(wm * 64 + mi * 16 + l16) * 40 + quad * 8];
#pragma unroll
    for (int ni = 0; ni < 4; ni++)
      b_frag[ni] = *(const short8*)&Bs[(wn * 64 + ni * 16 + l16) * 40 + quad * 8];
#pragma unroll
    for (int mi = 0; mi < 4; mi++)
#pragma unroll
      for (int ni = 0; ni < 4; ni++)
        acc[mi][ni] = __builtin_amdgcn_mfma_f32_16x16x32_bf16(a_frag[mi], b_frag[ni], acc[mi][ni], 0, 0, 0);
    __syncthreads();
  }

  // epilogue.  C[row=quad*4+reg (M), col=lane&15 (N)] per 16x16 tile (m89/m91 layout).
#pragma unroll
  for (int mi = 0; mi < 4; mi++)
#pragma unroll
    for (int ni = 0; ni < 4; ni++)
#pragma unroll
      for (int r = 0; r < 4; r++) {
        int m = m0 + wm * 64 + mi * 16 + quad * 4 + r;
        int n = n0 + wn * 64 + ni * 16 + l16;
        float val = acc[mi][ni][r];
        if (EPI == 0) {
          int b = m >> 11, s = m & 2047;
          int proj = n >> 10, rem = n & 1023, h = rem >> 6, d = rem & 63;
          size_t bh = (size_t)(b * NH + h);
          if (proj == 0)      qo[(bh * SEQ + s) * HD + d] = f2bf(val);
          else if (proj == 1) ko[(bh * SEQ + s) * HD + d] = f2bf(val);
          else                vto[(bh * HD + d) * SEQ + s] = f2bf(val);
        } else {
          outf[(size_t)m * EMB + n] = val + bias[n];
        }
      }
}

// ---------------- flash attention: per (qtile, h, b); 128 Q rows / block, 4 waves x 32 rows ----------------
__global__ __launch_bounds__(256) void attn_kernel(
    const unsigned short* __restrict__ qg, const unsigned short* __restrict__ kg,
    const unsigned short* __restrict__ vtg, const float* __restrict__ tw,
    unsigned short* __restrict__ aog) {
  __shared__ unsigned short Ks[128 * 72];   // K tile [key][d], stride 72 (144B rows)
  __shared__ unsigned short Vs[64 * 136];   // V^T tile [d][key], stride 136 (272B rows)
  __shared__ unsigned short Ps[128 * 136];  // P tile [q][key]; also reused to stage Q (stride 72)

  int tid = threadIdx.x;
  int lane = tid & 63, wid = tid >> 6;
  int quad = lane >> 4, l16 = lane & 15;
  int qt = blockIdx.x, h = blockIdx.y, b = blockIdx.z;
  int bh = b * NH + h;
  const unsigned short* qbase = qg + (size_t)bh * SEQ * HD + (size_t)qt * 128 * HD;
  const unsigned short* kbase = kg + (size_t)bh * SEQ * HD;
  const unsigned short* vbase = vtg + (size_t)bh * HD * SEQ;
  float scale = tw[bh];

  // stage Q tile (128x64) into Ps region at stride 72, pull A-fragments into regs
#pragma unroll
  for (int c = 0; c < 4; c++) {
    int flat = c * 2048 + tid * 8;
    int r = flat >> 6, col = flat & 63;
    *(uint4*)&Ps[r * 72 + col] = *(const uint4*)&qbase[flat];
  }
  __syncthreads();
  short8 a_q[2][2];
#pragma unroll
  for (int mi = 0; mi < 2; mi++)
#pragma unroll
    for (int kk = 0; kk < 2; kk++)
      a_q[mi][kk] = *(const short8*)&Ps[(wid * 32 + mi * 16 + l16) * 72 + kk * 32 + quad * 8];

  floatx4 O[2][4];
  float m_run[2][4], l_run[2][4];
#pragma unroll
  for (int mi = 0; mi < 2; mi++)
#pragma unroll
    for (int r = 0; r < 4; r++) { m_run[mi][r] = -1e30f; l_run[mi][r] = 0.f; }
#pragma unroll
  for (int mi = 0; mi < 2; mi++)
#pragma unroll
    for (int di = 0; di < 4; di++)
#pragma unroll
      for (int r = 0; r < 4; r++) O[mi][di][r] = 0.f;

  for (int kb = 0; kb < 16; kb++) {
    __syncthreads();   // prior iteration's Ks/Vs reads done
#pragma unroll
    for (int c = 0; c < 4; c++) {
      int flat = c * 2048 + tid * 8;
      int r = flat >> 6, col = flat & 63;
      *(uint4*)&Ks[r * 72 + col] = *(const uint4*)&kbase[(size_t)kb * 8192 + flat];
      int d = flat >> 7, j = flat & 127;
      *(uint4*)&Vs[d * 136 + j] = *(const uint4*)&vbase[(size_t)d * SEQ + kb * 128 + j];
    }
    __syncthreads();

    // S = Q @ K^T for this wave's 32 rows x 128 keys
    floatx4 sacc[2][8];
#pragma unroll
    for (int mi = 0; mi < 2; mi++)
#pragma unroll
      for (int ni = 0; ni < 8; ni++)
#pragma unroll
        for (int r = 0; r < 4; r++) sacc[mi][ni][r] = 0.f;
#pragma unroll
    for (int kk = 0; kk < 2; kk++)
#pragma unroll
      for (int ni = 0; ni < 8; ni++) {
        short8 b_k = *(const short8*)&Ks[(ni * 16 + l16) * 72 + kk * 32 + quad * 8];
#pragma unroll
        for (int mi = 0; mi < 2; mi++)
          sacc[mi][ni] = __builtin_amdgcn_mfma_f32_16x16x32_bf16(a_q[mi][kk], b_k, sacc[mi][ni], 0, 0, 0);
      }

    // online softmax (row stats wave-internal: 16-lane shuffle groups)
#pragma unroll
    for (int mi = 0; mi < 2; mi++)
#pragma unroll
      for (int r = 0; r < 4; r++) {
        float mx = -1e30f;
#pragma unroll
        for (int ni = 0; ni < 8; ni++) {
          float v = sacc[mi][ni][r] * scale;
          sacc[mi][ni][r] = v;
          mx = fmaxf(mx, v);
        }
#pragma unroll
        for (int off = 1; off < 16; off <<= 1) mx = fmaxf(mx, __shfl_xor(mx, off, 16));
        float mnew = fmaxf(m_run[mi][r], mx);
        float alpha = __expf(m_run[mi][r] - mnew);
        m_run[mi][r] = mnew;
        float rs = 0.f;
#pragma unroll
        for (int ni = 0; ni < 8; ni++) {
          float p = __expf(sacc[mi][ni][r] - mnew);
          sacc[mi][ni][r] = p;
          rs += p;
        }
#pragma unroll
        for (int off = 1; off < 16; off <<= 1) rs += __shfl_xor(rs, off, 16);
        l_run[mi][r] = l_run[mi][r] * alpha + rs;
#pragma unroll
        for (int di = 0; di < 4; di++) O[mi][di][r] *= alpha;
      }

    // P: C-layout regs -> LDS [q][key] bf16 (A-operand layout for PV); wave-private rows
#pragma unroll
    for (int mi = 0; mi < 2; mi++)
#pragma unroll
      for (int ni = 0; ni < 8; ni++)
#pragma unroll
        for (int r = 0; r < 4; r++)
          Ps[(wid * 32 + mi * 16 + quad * 4 + r) * 136 + ni * 16 + l16] = f2bf(sacc[mi][ni][r]);

    // O += P @ V   (B-operand = V^T rows: n=d, k=key)
#pragma unroll
    for (int ks = 0; ks < 4; ks++) {
      short8 a_p[2];
#pragma unroll
      for (int mi = 0; mi < 2; mi++)
        a_p[mi] = *(const short8*)&Ps[(wid * 32 + mi * 16 + l16) * 136 + ks * 32 + quad * 8];
#pragma unroll
      for (int di = 0; di < 4; di++) {
        short8 b_v = *(const short8*)&Vs[(di * 16 + l16) * 136 + ks * 32 + quad * 8];
#pragma unroll
        for (int mi = 0; mi < 2; mi++)
          O[mi][di] = __builtin_amdgcn_mfma_f32_16x16x32_bf16(a_p[mi], b_v, O[mi][di], 0, 0, 0);
      }
    }
  }

  // epilogue: O / l, write attn_out[b, s, h, d] (bf16) = A-matrix for out-proj GEMM
#pragma unroll
  for (int mi = 0; mi < 2; mi++)
#pragma unroll
    for (int r = 0; r < 4; r++) {
      float inv = 1.f / l_run[mi][r];
      int s = qt * 128 + wid * 32 + mi * 16 + quad * 4 + r;
#pragma unroll
      for (int di = 0; di < 4; di++) {
        int d = di * 16 + l16;
        aog[((size_t)(b * SEQ + s) * NH + h) * HD + d] = f2bf(O[mi][di][r] * inv);
      }
    }
}

// ---------------- launch ----------------
extern "C" void kernel_launch(void* const* d_in, const int* in_sizes, int n_in,
                              void* d_out, int out_size, void* d_ws, size_t ws_size,
                              hipStream_t stream) {
  (void)in_sizes; (void)n_in; (void)out_size; (void)ws_size;
  const float* x  = (const float*)d_in[0];
  const float* te = (const float*)d_in[1];
  const float* Wq = (const float*)d_in[2];
  const float* Wk = (const float*)d_in[3];
  const float* Wv = (const float*)d_in[4];
  const float* Wo = (const float*)d_in[5];
  const float* bo = (const float*)d_in[6];
  const float* Wt = (const float*)d_in[7];
  const float* bt = (const float*)d_in[8];
  float* out = (float*)d_out;

  char* ws = (char*)d_ws;
  size_t off = 0;
  auto carve = [&](size_t bytes) -> void* {
    void* p = ws + off;
    off += (bytes + 255) & ~(size_t)255;
    return p;
  };
  float* twb            = (float*)carve(64 * sizeof(float));
  unsigned short* xb    = (unsigned short*)carve((size_t)MROWS * EMB * 2);
  unsigned short* wqkvt = (unsigned short*)carve((size_t)3 * EMB * EMB * 2);
  unsigned short* wot   = (unsigned short*)carve((size_t)EMB * EMB * 2);
  unsigned short* qb    = (unsigned short*)carve((size_t)MROWS * EMB * 2);
  unsigned short* kb    = (unsigned short*)carve((size_t)MROWS * EMB * 2);
  unsigned short* vtb   = (unsigned short*)carve((size_t)MROWS * EMB * 2);
  unsigned short* ao    = xb;  // alias: xb is dead after GEMM1

  time_weights_kernel<<<dim3(1), dim3(64), 0, stream>>>(te, Wt, bt, twb);
  convert_x_kernel<<<dim3(8192), dim3(256), 0, stream>>>((const float4*)x, xb);
  transpose_convert_kernel<<<dim3(32, 32), dim3(32, 8), 0, stream>>>(Wq, wqkvt);
  transpose_convert_kernel<<<dim3(32, 32), dim3(32, 8), 0, stream>>>(Wk, wqkvt + (size_t)EMB * EMB);
  transpose_convert_kernel<<<dim3(32, 32), dim3(32, 8), 0, stream>>>(Wv, wqkvt + (size_t)2 * EMB * EMB);
  transpose_convert_kernel<<<dim3(32, 32), dim3(32, 8), 0, stream>>>(Wo, wot);
  gemm_kernel<0><<<dim3(24, 64), dim3(256), 0, stream>>>(xb, wqkvt, qb, kb, vtb, nullptr, nullptr);
  attn_kernel<<<dim3(16, NH, NB), dim3(256), 0, stream>>>(qb, kb, vtb, twb, ao);
  gemm_kernel<1><<<dim3(8, 64), dim3(256), 0, stream>>>(ao, wot, nullptr, nullptr, nullptr, out, bo);
}

// Round 2
// 433.002 us; speedup vs baseline: 1.1334x; 1.1334x over previous
//
#include <hip/hip_runtime.h>
#include <cstdint>
#include <cstddef>
#include <math.h>

// ---- problem constants ----
#define EMB   1024
#define NH    16
#define HD    64
#define SEQ   2048
#define NB    4
#define MROWS 8192   // NB*SEQ

typedef short short8 __attribute__((ext_vector_type(8)));
typedef float floatx4 __attribute__((ext_vector_type(4)));

__device__ __forceinline__ unsigned short f2bf(float f) {
  unsigned int u = __float_as_uint(f);
  u = u + 0x7fffu + ((u >> 16) & 1u);
  return (unsigned short)(u >> 16);
}

// ---------------- time weights: softmax(time_enc @ Wt + bt) * (1/sqrt(D)) * log2(e) ----------------
// log2(e) folded so attention can use raw exp2 (v_exp_f32) with Q pre-scaled.
__global__ void time_weights_kernel(const float* __restrict__ te, const float* __restrict__ Wt,
                                    const float* __restrict__ bt, float* __restrict__ tw) {
  int t = threadIdx.x;           // 64 threads = 1 wave; t = b*16 + h
  int b = t >> 4, h = t & 15;
  float acc = bt[h];
  for (int i = 0; i < 128; i++) acc += te[b * 128 + i] * Wt[i * 16 + h];
  float m = acc;
  for (int off = 1; off < 16; off <<= 1) m = fmaxf(m, __shfl_xor(m, off, 16));
  float e = __expf(acc - m);
  float s = e;
  for (int off = 1; off < 16; off <<= 1) s += __shfl_xor(s, off, 16);
  tw[t] = (e / s) * 0.125f * 1.4426950408889634f;  // 1/sqrt(64) * log2(e)
}

// ---------------- x (fp32) -> bf16 ----------------
__global__ void convert_x_kernel(const float4* __restrict__ x, unsigned short* __restrict__ out) {
  int i = blockIdx.x * blockDim.x + threadIdx.x;   // exactly 2097152 threads
  float4 v = x[i];
  union { unsigned short u[4]; uint2 p; } o;
  o.u[0] = f2bf(v.x); o.u[1] = f2bf(v.y); o.u[2] = f2bf(v.z); o.u[3] = f2bf(v.w);
  *(uint2*)&out[(size_t)i * 4] = o.p;
}

// ---------------- W [K][N] fp32 -> W^T [N][K] bf16 (tiled transpose) ----------------
__global__ void transpose_convert_kernel(const float* __restrict__ W, unsigned short* __restrict__ out) {
  __shared__ float tile[32][33];
  int k0 = blockIdx.x * 32;
  int n0 = blockIdx.y * 32;
  int tx = threadIdx.x;   // 0..31
  int ty = threadIdx.y;   // 0..7
#pragma unroll
  for (int i = 0; i < 4; i++) {
    int k = ty + i * 8;
    tile[k][tx] = W[(size_t)(k0 + k) * EMB + n0 + tx];
  }
  __syncthreads();
#pragma unroll
  for (int i = 0; i < 4; i++) {
    int n = ty + i * 8;
    out[(size_t)(n0 + n) * EMB + k0 + tx] = f2bf(tile[tx][n]);
  }
}

// ---------------- GEMM: C[M][N] = A[M][K=1024] @ Bt[N][K=1024]^T ----------------
// 128x128 block tile, BK=32, 4 waves (2x2), each wave 64x64 via 4x4 MFMA 16x16x32 tiles.
// EPI==0: scatter to q[b,h,s,d] (pre-scaled by tw), k[b,h,s,d], vt[b,h,d,s] (bf16).  N=3072.
// EPI==1: out fp32 = acc + bias[n].  N=1024.
template <int EPI>
__global__ __launch_bounds__(256) void gemm_kernel(
    const unsigned short* __restrict__ A, const unsigned short* __restrict__ Bt,
    unsigned short* __restrict__ qo, unsigned short* __restrict__ ko, unsigned short* __restrict__ vto,
    float* __restrict__ outf, const float* __restrict__ bias, const float* __restrict__ tw) {
  __shared__ unsigned short As[128 * 40];   // +8 pad: row stride 80 B (16B-aligned, 2-way banks)
  __shared__ unsigned short Bs[128 * 40];

  int tid = threadIdx.x;
  int lane = tid & 63, wid = tid >> 6;
  int quad = lane >> 4, l16 = lane & 15;
  int wm = wid >> 1, wn = wid & 1;
  int m0 = blockIdx.y * 128, n0 = blockIdx.x * 128;

  floatx4 acc[4][4];
#pragma unroll
  for (int mi = 0; mi < 4; mi++)
#pragma unroll
    for (int ni = 0; ni < 4; ni++)
#pragma unroll
      for (int r = 0; r < 4; r++) acc[mi][ni][r] = 0.f;

  for (int k0 = 0; k0 < 1024; k0 += 32) {
    // stage 128x32 tiles of A and Bt
#pragma unroll
    for (int c = 0; c < 2; c++) {
      int flat = c * 2048 + tid * 8;
      int r = flat >> 5, col = flat & 31;
      *(uint4*)&As[r * 40 + col] = *(const uint4*)&A[(size_t)(m0 + r) * 1024 + k0 + col];
      *(uint4*)&Bs[r * 40 + col] = *(const uint4*)&Bt[(size_t)(n0 + r) * 1024 + k0 + col];
    }
    __syncthreads();

    short8 a_frag[4], b_frag[4];
#pragma unroll
    for (int mi = 0; mi < 4; mi++)
      a_frag[mi] = *(const short8*)&As[(wm * 64 + mi * 16 + l16) * 40 + quad * 8];
#pragma unroll
    for (int ni = 0; ni < 4; ni++)
      b_frag[ni] = *(const short8*)&Bs[(wn * 64 + ni * 16 + l16) * 40 + quad * 8];
#pragma unroll
    for (int mi = 0; mi < 4; mi++)
#pragma unroll
      for (int ni = 0; ni < 4; ni++)
        acc[mi][ni] = __builtin_amdgcn_mfma_f32_16x16x32_bf16(a_frag[mi], b_frag[ni], acc[mi][ni], 0, 0, 0);
    __syncthreads();
  }

  // epilogue.  C[row=quad*4+reg (M), col=lane&15 (N)] per 16x16 tile (m89/m91 layout).
#pragma unroll
  for (int mi = 0; mi < 4; mi++)
#pragma unroll
    for (int ni = 0; ni < 4; ni++)
#pragma unroll
      for (int r = 0; r < 4; r++) {
        int m = m0 + wm * 64 + mi * 16 + quad * 4 + r;
        int n = n0 + wn * 64 + ni * 16 + l16;
        float val = acc[mi][ni][r];
        if (EPI == 0) {
          int b = m >> 11, s = m & 2047;
          int proj = n >> 10, rem = n & 1023, h = rem >> 6, d = rem & 63;
          size_t bh = (size_t)(b * NH + h);
          if (proj == 0)      qo[(bh * SEQ + s) * HD + d] = f2bf(val * tw[bh]);
          else if (proj == 1) ko[(bh * SEQ + s) * HD + d] = f2bf(val);
          else                vto[(bh * HD + d) * SEQ + s] = f2bf(val);
        } else {
          outf[(size_t)m * EMB + n] = val + bias[n];
        }
      }
}

// ---------------- flash attention (no-max softmax: scores provably bounded) ----------------
// per (qtile, h, b); 128 Q rows / block, 4 waves x 32 rows. Q is pre-scaled by tw*log2e,
// so P = exp2(S) directly; row-sum l accumulated per-lane, reduced once at the end.
__global__ __launch_bounds__(256) void attn_kernel(
    const unsigned short* __restrict__ qg, const unsigned short* __restrict__ kg,
    const unsigned short* __restrict__ vtg,
    unsigned short* __restrict__ aog) {
  __shared__ unsigned short Ks[128 * 72];      // 18432 B; K tile [key][d]; also stages Q at start
  __shared__ unsigned short Vs[64 * 136];      // 17408 B; V^T tile [d][key]
  __shared__ unsigned short Ps[4][32 * 72];    // 18432 B; per-wave P half-tile [qrow][64 keys]
  // total 54272 B -> 3 blocks/CU (3*54272 = 162816 <= 163840)

  int tid = threadIdx.x;
  int lane = tid & 63, wid = tid >> 6;
  int quad = lane >> 4, l16 = lane & 15;
  int qt = blockIdx.x, h = blockIdx.y, b = blockIdx.z;
  int bh = b * NH + h;
  const unsigned short* qbase = qg + (size_t)bh * SEQ * HD + (size_t)qt * 128 * HD;
  const unsigned short* kbase = kg + (size_t)bh * SEQ * HD;
  const unsigned short* vbase = vtg + (size_t)bh * HD * SEQ;

  // stage Q tile (128x64) into Ks region at stride 72, pull A-fragments into regs
#pragma unroll
  for (int c = 0; c < 4; c++) {
    int flat = c * 2048 + tid * 8;
    int r = flat >> 6, col = flat & 63;
    *(uint4*)&Ks[r * 72 + col] = *(const uint4*)&qbase[flat];
  }
  __syncthreads();
  short8 a_q[2][2];
#pragma unroll
  for (int mi = 0; mi < 2; mi++)
#pragma unroll
    for (int kk = 0; kk < 2; kk++)
      a_q[mi][kk] = *(const short8*)&Ks[(wid * 32 + mi * 16 + l16) * 72 + kk * 32 + quad * 8];

  floatx4 O[2][4];
  float lsum[2][4];
#pragma unroll
  for (int mi = 0; mi < 2; mi++)
#pragma unroll
    for (int r = 0; r < 4; r++) lsum[mi][r] = 0.f;
#pragma unroll
  for (int mi = 0; mi < 2; mi++)
#pragma unroll
    for (int di = 0; di < 4; di++)
#pragma unroll
      for (int r = 0; r < 4; r++) O[mi][di][r] = 0.f;

  for (int kb = 0; kb < 16; kb++) {
    __syncthreads();   // prior iteration's Ks/Vs reads (and initial a_q reads) done
#pragma unroll
    for (int c = 0; c < 4; c++) {
      int flat = c * 2048 + tid * 8;
      int r = flat >> 6, col = flat & 63;
      *(uint4*)&Ks[r * 72 + col] = *(const uint4*)&kbase[(size_t)kb * 8192 + flat];
      int d = flat >> 7, j = flat & 127;
      *(uint4*)&Vs[d * 136 + j] = *(const uint4*)&vbase[(size_t)d * SEQ + kb * 128 + j];
    }
    __syncthreads();

    // S = Q @ K^T for this wave's 32 rows x 128 keys (Q already carries tw*log2e/sqrt(D))
    floatx4 sacc[2][8];
#pragma unroll
    for (int mi = 0; mi < 2; mi++)
#pragma unroll
      for (int ni = 0; ni < 8; ni++)
#pragma unroll
        for (int r = 0; r < 4; r++) sacc[mi][ni][r] = 0.f;
#pragma unroll
    for (int kk = 0; kk < 2; kk++)
#pragma unroll
      for (int ni = 0; ni < 8; ni++) {
        short8 b_k = *(const short8*)&Ks[(ni * 16 + l16) * 72 + kk * 32 + quad * 8];
#pragma unroll
        for (int mi = 0; mi < 2; mi++)
          sacc[mi][ni] = __builtin_amdgcn_mfma_f32_16x16x32_bf16(a_q[mi][kk], b_k, sacc[mi][ni], 0, 0, 0);
      }

    // P = exp2(S); no max subtraction (|S| <~ 10), no cross-lane work in the loop
#pragma unroll
    for (int mi = 0; mi < 2; mi++)
#pragma unroll
      for (int ni = 0; ni < 8; ni++)
#pragma unroll
        for (int r = 0; r < 4; r++) {
          float p = exp2f(sacc[mi][ni][r]);
          sacc[mi][ni][r] = p;
          lsum[mi][r] += p;
        }

    // PV in two 64-key halves through the wave-private P buffer
#pragma unroll
    for (int kh = 0; kh < 2; kh++) {
      // P: C-layout regs -> LDS [qrow][key] bf16 (A-operand layout)
#pragma unroll
      for (int mi = 0; mi < 2; mi++)
#pragma unroll
        for (int ni = 0; ni < 4; ni++)
#pragma unroll
          for (int r = 0; r < 4; r++)
            Ps[wid][(mi * 16 + quad * 4 + r) * 72 + ni * 16 + l16] = f2bf(sacc[mi][kh * 4 + ni][r]);

      // O += P @ V   (B-operand = V^T rows: n=d, k=key)
#pragma unroll
      for (int ks = 0; ks < 2; ks++) {
        short8 a_p[2];
#pragma unroll
        for (int mi = 0; mi < 2; mi++)
          a_p[mi] = *(const short8*)&Ps[wid][(mi * 16 + l16) * 72 + ks * 32 + quad * 8];
#pragma unroll
        for (int di = 0; di < 4; di++) {
          short8 b_v = *(const short8*)&Vs[(di * 16 + l16) * 136 + kh * 64 + ks * 32 + quad * 8];
#pragma unroll
          for (int mi = 0; mi < 2; mi++)
            O[mi][di] = __builtin_amdgcn_mfma_f32_16x16x32_bf16(a_p[mi], b_v, O[mi][di], 0, 0, 0);
        }
      }
    }
  }

  // final row-sum reduction (once): sum lsum over the 16 l16 lanes
#pragma unroll
  for (int mi = 0; mi < 2; mi++)
#pragma unroll
    for (int r = 0; r < 4; r++) {
#pragma unroll
      for (int off = 1; off < 16; off <<= 1) lsum[mi][r] += __shfl_xor(lsum[mi][r], off, 16);
    }

  // epilogue: O / l, write attn_out[b, s, h, d] (bf16) = A-matrix for out-proj GEMM
#pragma unroll
  for (int mi = 0; mi < 2; mi++)
#pragma unroll
    for (int r = 0; r < 4; r++) {
      float inv = 1.f / lsum[mi][r];
      int s = qt * 128 + wid * 32 + mi * 16 + quad * 4 + r;
#pragma unroll
      for (int di = 0; di < 4; di++) {
        int d = di * 16 + l16;
        aog[((size_t)(b * SEQ + s) * NH + h) * HD + d] = f2bf(O[mi][di][r] * inv);
      }
    }
}

// ---------------- launch ----------------
extern "C" void kernel_launch(void* const* d_in, const int* in_sizes, int n_in,
                              void* d_out, int out_size, void* d_ws, size_t ws_size,
                              hipStream_t stream) {
  (void)in_sizes; (void)n_in; (void)out_size; (void)ws_size;
  const float* x  = (const float*)d_in[0];
  const float* te = (const float*)d_in[1];
  const float* Wq = (const float*)d_in[2];
  const float* Wk = (const float*)d_in[3];
  const float* Wv = (const float*)d_in[4];
  const float* Wo = (const float*)d_in[5];
  const float* bo = (const float*)d_in[6];
  const float* Wt = (const float*)d_in[7];
  const float* bt = (const float*)d_in[8];
  float* out = (float*)d_out;

  char* ws = (char*)d_ws;
  size_t off = 0;
  auto carve = [&](size_t bytes) -> void* {
    void* p = ws + off;
    off += (bytes + 255) & ~(size_t)255;
    return p;
  };
  float* twb            = (float*)carve(64 * sizeof(float));
  unsigned short* xb    = (unsigned short*)carve((size_t)MROWS * EMB * 2);
  unsigned short* wqkvt = (unsigned short*)carve((size_t)3 * EMB * EMB * 2);
  unsigned short* wot   = (unsigned short*)carve((size_t)EMB * EMB * 2);
  unsigned short* qb    = (unsigned short*)carve((size_t)MROWS * EMB * 2);
  unsigned short* kb    = (unsigned short*)carve((size_t)MROWS * EMB * 2);
  unsigned short* vtb   = (unsigned short*)carve((size_t)MROWS * EMB * 2);
  unsigned short* ao    = xb;  // alias: xb is dead after GEMM1

  time_weights_kernel<<<dim3(1), dim3(64), 0, stream>>>(te, Wt, bt, twb);
  convert_x_kernel<<<dim3(8192), dim3(256), 0, stream>>>((const float4*)x, xb);
  transpose_convert_kernel<<<dim3(32, 32), dim3(32, 8), 0, stream>>>(Wq, wqkvt);
  transpose_convert_kernel<<<dim3(32, 32), dim3(32, 8), 0, stream>>>(Wk, wqkvt + (size_t)EMB * EMB);
  transpose_convert_kernel<<<dim3(32, 32), dim3(32, 8), 0, stream>>>(Wv, wqkvt + (size_t)2 * EMB * EMB);
  transpose_convert_kernel<<<dim3(32, 32), dim3(32, 8), 0, stream>>>(Wo, wot);
  gemm_kernel<0><<<dim3(24, 64), dim3(256), 0, stream>>>(xb, wqkvt, qb, kb, vtb, nullptr, nullptr, twb);
  attn_kernel<<<dim3(16, NH, NB), dim3(256), 0, stream>>>(qb, kb, vtb, ao);
  gemm_kernel<1><<<dim3(8, 64), dim3(256), 0, stream>>>(ao, wot, nullptr, nullptr, nullptr, out, bo, nullptr);
}

// Round 3
// 353.318 us; speedup vs baseline: 1.3891x; 1.2255x over previous
//
#include <hip/hip_runtime.h>
#include <cstdint>
#include <cstddef>

// ---- problem constants ----
#define EMB   1024
#define NH    16
#define HD    64
#define SEQ   2048
#define NB    4
#define MROWS 8192   // NB*SEQ

typedef short short8 __attribute__((ext_vector_type(8)));
typedef float floatx4 __attribute__((ext_vector_type(4)));

// round-to-nearest (ties away) bf16: 1 VALU op + hi16 store
__device__ __forceinline__ unsigned short f2bf(float f) {
  return (unsigned short)((__float_as_uint(f) + 0x8000u) >> 16);
}

// async global->LDS, 16B per lane; LDS dest = uniform base + lane*16
__device__ __forceinline__ void load16_lds(const unsigned short* g, unsigned short* l) {
  __builtin_amdgcn_global_load_lds((const __attribute__((address_space(1))) void*)g,
                                   (__attribute__((address_space(3))) void*)l, 16, 0, 0);
}

// ---------------- time weights: softmax(time_enc @ Wt + bt) * (1/sqrt(D)) * log2(e) ----------------
__global__ void time_weights_kernel(const float* __restrict__ te, const float* __restrict__ Wt,
                                    const float* __restrict__ bt, float* __restrict__ tw) {
  int t = threadIdx.x;           // 64 threads = 1 wave; t = b*16 + h
  int b = t >> 4, h = t & 15;
  float acc = bt[h];
  for (int i = 0; i < 128; i++) acc += te[b * 128 + i] * Wt[i * 16 + h];
  float m = acc;
  for (int off = 1; off < 16; off <<= 1) m = fmaxf(m, __shfl_xor(m, off, 16));
  float e = __expf(acc - m);
  float s = e;
  for (int off = 1; off < 16; off <<= 1) s += __shfl_xor(s, off, 16);
  tw[t] = (e / s) * 0.125f * 1.4426950408889634f;  // 1/sqrt(64) * log2(e)
}

// ---------------- x (fp32) -> bf16 ----------------
__global__ void convert_x_kernel(const float4* __restrict__ x, unsigned short* __restrict__ out) {
  int i = blockIdx.x * blockDim.x + threadIdx.x;   // exactly 2097152 threads
  float4 v = x[i];
  unsigned int u0 = __float_as_uint(v.x) + 0x8000u, u1 = __float_as_uint(v.y) + 0x8000u;
  unsigned int u2 = __float_as_uint(v.z) + 0x8000u, u3 = __float_as_uint(v.w) + 0x8000u;
  uint2 p;
  p.x = (u0 >> 16) | (u1 & 0xffff0000u);
  p.y = (u2 >> 16) | (u3 & 0xffff0000u);
  *(uint2*)&out[(size_t)i * 4] = p;
}

// ---------------- W [K][N] fp32 -> W^T [N][K] bf16 (tiled transpose) ----------------
__global__ void transpose_convert_kernel(const float* __restrict__ W, unsigned short* __restrict__ out) {
  __shared__ float tile[32][33];
  int k0 = blockIdx.x * 32;
  int n0 = blockIdx.y * 32;
  int tx = threadIdx.x;   // 0..31
  int ty = threadIdx.y;   // 0..7
#pragma unroll
  for (int i = 0; i < 4; i++) {
    int k = ty + i * 8;
    tile[k][tx] = W[(size_t)(k0 + k) * EMB + n0 + tx];
  }
  __syncthreads();
#pragma unroll
  for (int i = 0; i < 4; i++) {
    int n = ty + i * 8;
    out[(size_t)(n0 + n) * EMB + k0 + tx] = f2bf(tile[tx][n]);
  }
}

// ---------------- GEMM: C[M][N] = A[M][K=1024] @ Bt[N][K=1024]^T ----------------
// m97 structure: 128x128 tile, BK=32, global_load_lds width=16, unpadded LDS with
// XOR swizzle granule ^= (row>>1)&3 (2-way bank classes on b128 frag reads = free).
// EPI==0: scatter to q[b,h,s,d] (pre-scaled by tw), k[b,h,s,d], vt[b,h,d,s] (bf16). N=3072.
// EPI==1: out fp32 = acc + bias[n].  N=1024.
template <int EPI>
__global__ __launch_bounds__(256) void gemm_kernel(
    const unsigned short* __restrict__ A, const unsigned short* __restrict__ Bt,
    unsigned short* __restrict__ qo, unsigned short* __restrict__ ko, unsigned short* __restrict__ vto,
    float* __restrict__ outf, const float* __restrict__ bias, const float* __restrict__ tw) {
  __shared__ unsigned short As[128 * 32];
  __shared__ unsigned short Bs[128 * 32];

  int tid = threadIdx.x;
  int lane = tid & 63, wid = tid >> 6;
  int quad = lane >> 4, l16 = lane & 15;
  int wm = wid >> 1, wn = wid & 1;
  int m0 = blockIdx.y * 128, n0 = blockIdx.x * 128;

  // staging: wave stages rows wid*32 + c*16 + lane/4; lane lands at LDS slot lane*16B.
  // LDS phys granule g holds global col8 = g ^ ((row>>1)&3).
  const unsigned short* gA[2];
  const unsigned short* gB[2];
  unsigned short* lA[2];
  unsigned short* lB[2];
#pragma unroll
  for (int c = 0; c < 2; c++) {
    int row = wid * 32 + c * 16 + (lane >> 2);
    int col = (((lane & 3) ^ ((row >> 1) & 3)) * 8);
    gA[c] = A + (size_t)(m0 + row) * 1024 + col;
    gB[c] = Bt + (size_t)(n0 + row) * 1024 + col;
    lA[c] = &As[(wid * 32 + c * 16) * 32];
    lB[c] = &Bs[(wid * 32 + c * 16) * 32];
  }

  // frag reads: logical granule quad -> phys quad ^ ((row>>1)&3); (row>>1)&3 == (l16>>1)&3
  int aoff = (quad ^ ((l16 >> 1) & 3)) * 8;

  floatx4 acc[4][4];
#pragma unroll
  for (int mi = 0; mi < 4; mi++)
#pragma unroll
    for (int ni = 0; ni < 4; ni++)
#pragma unroll
      for (int r = 0; r < 4; r++) acc[mi][ni][r] = 0.f;

  for (int k0 = 0; k0 < 1024; k0 += 32) {
    __syncthreads();   // prior iteration's frag reads done in all waves
#pragma unroll
    for (int c = 0; c < 2; c++) {
      load16_lds(gA[c] + k0, lA[c]);
      load16_lds(gB[c] + k0, lB[c]);
    }
    __syncthreads();   // vmcnt(0) drain: staged data visible

    short8 a_frag[4], b_frag[4];
#pragma unroll
    for (int mi = 0; mi < 4; mi++)
      a_frag[mi] = *(const short8*)&As[(wm * 64 + mi * 16 + l16) * 32 + aoff];
#pragma unroll
    for (int ni = 0; ni < 4; ni++)
      b_frag[ni] = *(const short8*)&Bs[(wn * 64 + ni * 16 + l16) * 32 + aoff];
#pragma unroll
    for (int mi = 0; mi < 4; mi++)
#pragma unroll
      for (int ni = 0; ni < 4; ni++)
        acc[mi][ni] = __builtin_amdgcn_mfma_f32_16x16x32_bf16(a_frag[mi], b_frag[ni], acc[mi][ni], 0, 0, 0);
  }

  // epilogue.  C[row=quad*4+r (M), col=l16 (N)] per 16x16 tile.
#pragma unroll
  for (int mi = 0; mi < 4; mi++)
#pragma unroll
    for (int ni = 0; ni < 4; ni++)
#pragma unroll
      for (int r = 0; r < 4; r++) {
        int m = m0 + wm * 64 + mi * 16 + quad * 4 + r;
        int n = n0 + wn * 64 + ni * 16 + l16;
        float val = acc[mi][ni][r];
        if (EPI == 0) {
          int b = m >> 11, s = m & 2047;
          int proj = n >> 10, rem = n & 1023, hh = rem >> 6, d = rem & 63;
          size_t bh = (size_t)(b * NH + hh);
          if (proj == 0)      qo[(bh * SEQ + s) * HD + d] = f2bf(val * tw[bh]);
          else if (proj == 1) ko[(bh * SEQ + s) * HD + d] = f2bf(val);
          else                vto[(bh * HD + d) * SEQ + s] = f2bf(val);
        } else {
          outf[(size_t)m * EMB + n] = val + bias[n];
        }
      }
}

// ---------------- flash attention (no-max softmax; O computed transposed) ----------------
// per (qtile, h, b); 128 Q rows / block, 4 waves x 32 rows; 64-key K-tiles (32 iters).
// Q pre-scaled by tw*log2e => P = exp2(S).  PV computed as O^T = (V^T)(P^T) by swapping
// MFMA operands: A = V^T-frag, B = P-frag (reads identical), so the epilogue lane holds
// a fixed qrow (=l16) and 4 consecutive d per reg-quad -> packed 8B stores + direct 1/l.
__global__ __launch_bounds__(256, 4) void attn_kernel(
    const unsigned short* __restrict__ qg, const unsigned short* __restrict__ kg,
    const unsigned short* __restrict__ vtg, unsigned short* __restrict__ aog) {
  __shared__ unsigned short Ks[64 * 64];    // 8192 B; [key][d], swizzle g^=row&7
  __shared__ unsigned short Vs[64 * 64];    // 8192 B; [d][key], swizzle g^=row&7
  __shared__ unsigned short Ps[4 * 1280];   // 10240 B; per-wave 32x32 P, stride 40, g^=(row>>2)&3
  // total 26624 B -> LDS allows >=4 blocks/CU; grid = 4 blocks/CU exactly (no tail)

  int tid = threadIdx.x;
  int lane = tid & 63, wid = tid >> 6;
  int quad = lane >> 4, l16 = lane & 15, l7 = lane & 7;
  int qt = blockIdx.x, h = blockIdx.y, b = blockIdx.z;
  int bh = b * NH + h;
  const unsigned short* qbase = qg + (size_t)bh * SEQ * HD + (size_t)qt * 128 * HD;
  const unsigned short* kbase = kg + (size_t)bh * SEQ * HD;
  const unsigned short* vbase = vtg + (size_t)bh * HD * SEQ;

  // Q A-fragments straight from global (one-time, 16B/lane coalesced within rows)
  short8 a_q[2][2];
#pragma unroll
  for (int mi = 0; mi < 2; mi++)
#pragma unroll
    for (int kk = 0; kk < 2; kk++)
      a_q[mi][kk] = *(const short8*)&qbase[(wid * 32 + mi * 16 + l16) * 64 + kk * 32 + quad * 8];

  // staging (global_load_lds): instr c covers rows wid*16 + c*8 + lane/8, granule lane&7
  const unsigned short* gK[2];
  const unsigned short* gV[2];
  unsigned short* lK[2];
  unsigned short* lV[2];
#pragma unroll
  for (int c = 0; c < 2; c++) {
    int row = wid * 16 + c * 8 + (lane >> 3);
    int gcol = ((lane & 7) ^ (row & 7)) * 8;
    gK[c] = kbase + row * 64 + gcol;            // + kb*4096 per iter
    gV[c] = vbase + (size_t)row * SEQ + gcol;   // + kb*64  per iter
    lK[c] = &Ks[(wid * 16 + c * 8) * 64];
    lV[c] = &Vs[(wid * 16 + c * 8) * 64];
  }

  // K/V frag reads: row base l16*64, phys granule (i*4+quad)^l7, tile-row imm
  int pg[2];
#pragma unroll
  for (int i = 0; i < 2; i++) pg[i] = l16 * 64 + (((i * 4 + quad) ^ l7) * 8);

  // Ps addressing (element offsets; row stride 40, granule ^= quad-of-row)
  int wbase = wid * 1280;
  int pwa[2];
#pragma unroll
  for (int ni2 = 0; ni2 < 2; ni2++)
    pwa[ni2] = wbase + quad * 160 + (((ni2 * 2 + (l16 >> 3)) ^ quad) * 8) + l7;
  int pra = wbase + l16 * 40 + ((quad ^ ((l16 >> 2) & 3)) * 8);

  floatx4 O[4][2];   // [di][mi]  (O^T: row=d, col=qrow)
  float lsum[2][4];
#pragma unroll
  for (int mi = 0; mi < 2; mi++)
#pragma unroll
    for (int r = 0; r < 4; r++) lsum[mi][r] = 0.f;
#pragma unroll
  for (int di = 0; di < 4; di++)
#pragma unroll
    for (int mi = 0; mi < 2; mi++)
#pragma unroll
      for (int r = 0; r < 4; r++) O[di][mi][r] = 0.f;

  for (int kb = 0; kb < 32; kb++) {
    __syncthreads();   // all waves' prior-iter LDS reads done
#pragma unroll
    for (int c = 0; c < 2; c++) {
      load16_lds(gK[c] + kb * 4096, lK[c]);
      load16_lds(gV[c] + kb * 64, lV[c]);
    }
    __syncthreads();   // staged tiles visible

    // S = Q @ K^T : 32 qrows x 64 keys per wave
    floatx4 sacc[2][4];
#pragma unroll
    for (int mi = 0; mi < 2; mi++)
#pragma unroll
      for (int ni = 0; ni < 4; ni++)
#pragma unroll
        for (int r = 0; r < 4; r++) sacc[mi][ni][r] = 0.f;
#pragma unroll
    for (int kk = 0; kk < 2; kk++)
#pragma unroll
      for (int ni = 0; ni < 4; ni++) {
        short8 b_k = *(const short8*)&Ks[ni * 1024 + pg[kk]];
#pragma unroll
        for (int mi = 0; mi < 2; mi++)
          sacc[mi][ni] = __builtin_amdgcn_mfma_f32_16x16x32_bf16(a_q[mi][kk], b_k, sacc[mi][ni], 0, 0, 0);
      }

    // exp2 + P store + PV, in two 32-key halves through the wave-private P buffer
#pragma unroll
    for (int kh = 0; kh < 2; kh++) {
#pragma unroll
      for (int mi = 0; mi < 2; mi++)
#pragma unroll
        for (int ni2 = 0; ni2 < 2; ni2++) {
          int ni = kh * 2 + ni2;
#pragma unroll
          for (int r = 0; r < 4; r++) {
            float p = __builtin_amdgcn_exp2f(sacc[mi][ni][r]);
            lsum[mi][r] += p;
            Ps[pwa[ni2] + mi * 640 + r * 40] = f2bf(p);
          }
        }
      // O^T += (V^T)(P^T):  A = V^T frag (m=d, k=key), B = P frag (n=qrow, k=key)
      short8 av[4], bp[2];
#pragma unroll
      for (int di = 0; di < 4; di++)
        av[di] = *(const short8*)&Vs[di * 1024 + pg[kh]];
#pragma unroll
      for (int mi = 0; mi < 2; mi++)
        bp[mi] = *(const short8*)&Ps[pra + mi * 640];
#pragma unroll
      for (int di = 0; di < 4; di++)
#pragma unroll
        for (int mi = 0; mi < 2; mi++)
          O[di][mi] = __builtin_amdgcn_mfma_f32_16x16x32_bf16(av[di], bp[mi], O[di][mi], 0, 0, 0);
    }
  }

  // row-sum: reduce per-lane partials over the 16 l16 lanes (once)
#pragma unroll
  for (int mi = 0; mi < 2; mi++)
#pragma unroll
    for (int r = 0; r < 4; r++) {
#pragma unroll
      for (int off = 1; off < 16; off <<= 1) lsum[mi][r] += __shfl_xor(lsum[mi][r], off);
    }

  // redistribute l by qrow via wave-private LDS (Ps region is dead)
  float* psf = (float*)&Ps[wbase];
  if (l16 == 0) {
#pragma unroll
    for (int mi = 0; mi < 2; mi++)
#pragma unroll
      for (int r = 0; r < 4; r++) psf[mi * 16 + quad * 4 + r] = lsum[mi][r];
  }
  float inv[2];
#pragma unroll
  for (int mi = 0; mi < 2; mi++) inv[mi] = 1.0f / psf[mi * 16 + l16];

  // epilogue: lane holds qrow = mi*16+l16, d = di*16+quad*4+r -> 4 packed bf16 per store
#pragma unroll
  for (int mi = 0; mi < 2; mi++) {
    int s = qt * 128 + wid * 32 + mi * 16 + l16;
    size_t rowbase = ((size_t)(b * SEQ + s) * NH + h) * HD;
#pragma unroll
    for (int di = 0; di < 4; di++) {
      unsigned int u0 = __float_as_uint(O[di][mi][0] * inv[mi]) + 0x8000u;
      unsigned int u1 = __float_as_uint(O[di][mi][1] * inv[mi]) + 0x8000u;
      unsigned int u2 = __float_as_uint(O[di][mi][2] * inv[mi]) + 0x8000u;
      unsigned int u3 = __float_as_uint(O[di][mi][3] * inv[mi]) + 0x8000u;
      uint2 w;
      w.x = (u0 >> 16) | (u1 & 0xffff0000u);
      w.y = (u2 >> 16) | (u3 & 0xffff0000u);
      *(uint2*)&aog[rowbase + di * 16 + quad * 4] = w;
    }
  }
}

// ---------------- launch ----------------
extern "C" void kernel_launch(void* const* d_in, const int* in_sizes, int n_in,
                              void* d_out, int out_size, void* d_ws, size_t ws_size,
                              hipStream_t stream) {
  (void)in_sizes; (void)n_in; (void)out_size; (void)ws_size;
  const float* x  = (const float*)d_in[0];
  const float* te = (const float*)d_in[1];
  const float* Wq = (const float*)d_in[2];
  const float* Wk = (const float*)d_in[3];
  const float* Wv = (const float*)d_in[4];
  const float* Wo = (const float*)d_in[5];
  const float* bo = (const float*)d_in[6];
  const float* Wt = (const float*)d_in[7];
  const float* bt = (const float*)d_in[8];
  float* out = (float*)d_out;

  char* ws = (char*)d_ws;
  size_t off = 0;
  auto carve = [&](size_t bytes) -> void* {
    void* p = ws + off;
    off += (bytes + 255) & ~(size_t)255;
    return p;
  };
  float* twb            = (float*)carve(64 * sizeof(float));
  unsigned short* xb    = (unsigned short*)carve((size_t)MROWS * EMB * 2);
  unsigned short* wqkvt = (unsigned short*)carve((size_t)3 * EMB * EMB * 2);
  unsigned short* wot   = (unsigned short*)carve((size_t)EMB * EMB * 2);
  unsigned short* qb    = (unsigned short*)carve((size_t)MROWS * EMB * 2);
  unsigned short* kb    = (unsigned short*)carve((size_t)MROWS * EMB * 2);
  unsigned short* vtb   = (unsigned short*)carve((size_t)MROWS * EMB * 2);
  unsigned short* ao    = xb;  // alias: xb is dead after GEMM0

  time_weights_kernel<<<dim3(1), dim3(64), 0, stream>>>(te, Wt, bt, twb);
  convert_x_kernel<<<dim3(8192), dim3(256), 0, stream>>>((const float4*)x, xb);
  transpose_convert_kernel<<<dim3(32, 32), dim3(32, 8), 0, stream>>>(Wq, wqkvt);
  transpose_convert_kernel<<<dim3(32, 32), dim3(32, 8), 0, stream>>>(Wk, wqkvt + (size_t)EMB * EMB);
  transpose_convert_kernel<<<dim3(32, 32), dim3(32, 8), 0, stream>>>(Wv, wqkvt + (size_t)2 * EMB * EMB);
  transpose_convert_kernel<<<dim3(32, 32), dim3(32, 8), 0, stream>>>(Wo, wot);
  gemm_kernel<0><<<dim3(24, 64), dim3(256), 0, stream>>>(xb, wqkvt, qb, kb, vtb, nullptr, nullptr, twb);
  attn_kernel<<<dim3(16, NH, NB), dim3(256), 0, stream>>>(qb, kb, vtb, ao);
  gemm_kernel<1><<<dim3(8, 64), dim3(256), 0, stream>>>(ao, wot, nullptr, nullptr, nullptr, out, bo, nullptr);
}

// Round 5
// 324.553 us; speedup vs baseline: 1.5122x; 1.0886x over previous
//
#include <hip/hip_runtime.h>
#include <cstdint>
#include <cstddef>

// ---- problem constants ----
#define EMB   1024
#define NH    16
#define HD    64
#define SEQ   2048
#define NB    4
#define MROWS 8192   // NB*SEQ

typedef short short8 __attribute__((ext_vector_type(8)));
typedef float floatx4 __attribute__((ext_vector_type(4)));

// round-to-nearest bf16: 1 VALU op + hi16 store
__device__ __forceinline__ unsigned short f2bf(float f) {
  return (unsigned short)((__float_as_uint(f) + 0x8000u) >> 16);
}

// async global->LDS, 16B per lane; LDS dest = wave-uniform base + lane*16
__device__ __forceinline__ void load16_lds(const unsigned short* g, unsigned short* l) {
  __builtin_amdgcn_global_load_lds((const __attribute__((address_space(1))) void*)g,
                                   (__attribute__((address_space(3))) void*)l, 16, 0, 0);
}

// ---------------- time weights: softmax(time_enc @ Wt + bt) * (1/sqrt(D)) * log2(e) ----------------
__global__ void time_weights_kernel(const float* __restrict__ te, const float* __restrict__ Wt,
                                    const float* __restrict__ bt, float* __restrict__ tw) {
  int t = threadIdx.x;           // 64 threads = 1 wave; t = b*16 + h
  int b = t >> 4, h = t & 15;
  float acc = bt[h];
  for (int i = 0; i < 128; i++) acc += te[b * 128 + i] * Wt[i * 16 + h];
  float m = acc;
  for (int off = 1; off < 16; off <<= 1) m = fmaxf(m, __shfl_xor(m, off, 16));
  float e = __expf(acc - m);
  float s = e;
  for (int off = 1; off < 16; off <<= 1) s += __shfl_xor(s, off, 16);
  tw[t] = (e / s) * 0.125f * 1.4426950408889634f;  // 1/sqrt(64) * log2(e)
}

// ---------------- x (fp32) -> bf16 ----------------
__global__ void convert_x_kernel(const float4* __restrict__ x, unsigned short* __restrict__ out) {
  int i = blockIdx.x * blockDim.x + threadIdx.x;   // exactly 2097152 threads
  float4 v = x[i];
  unsigned int u0 = __float_as_uint(v.x) + 0x8000u, u1 = __float_as_uint(v.y) + 0x8000u;
  unsigned int u2 = __float_as_uint(v.z) + 0x8000u, u3 = __float_as_uint(v.w) + 0x8000u;
  uint2 p;
  p.x = (u0 >> 16) | (u1 & 0xffff0000u);
  p.y = (u2 >> 16) | (u3 & 0xffff0000u);
  *(uint2*)&out[(size_t)i * 4] = p;
}

// ---------------- all four W [K][N] fp32 -> W^T [N][K] bf16, one launch ----------------
__global__ void transpose_convert4_kernel(const float* __restrict__ Wq, const float* __restrict__ Wk,
                                          const float* __restrict__ Wv, const float* __restrict__ Wo,
                                          unsigned short* __restrict__ wqkvt, unsigned short* __restrict__ wot) {
  __shared__ float tile[32][33];
  int z = blockIdx.z;
  const float* W = (z == 0) ? Wq : (z == 1) ? Wk : (z == 2) ? Wv : Wo;
  unsigned short* out = (z < 3) ? (wqkvt + (size_t)z * EMB * EMB) : wot;
  int k0 = blockIdx.x * 32;
  int n0 = blockIdx.y * 32;
  int tx = threadIdx.x;   // 0..31
  int ty = threadIdx.y;   // 0..7
#pragma unroll
  for (int i = 0; i < 4; i++) {
    int k = ty + i * 8;
    tile[k][tx] = W[(size_t)(k0 + k) * EMB + n0 + tx];
  }
  __syncthreads();
#pragma unroll
  for (int i = 0; i < 4; i++) {
    int n = ty + i * 8;
    out[(size_t)(n0 + n) * EMB + k0 + tx] = f2bf(tile[tx][n]);
  }
}

// ---------------- GEMM: C[M][N] = A[M][K=1024] @ Bt[N][K=1024]^T ----------------
// 128x128 tile, BK=64 (16 K-iters), global_load_lds width=16, unpadded stride-64 LDS
// with 3-bit XOR granule swizzle g ^= (row&7) (2-way per 16-lane phase = free).
// EPI==0: scatter to q[b,h,s,d] (pre-scaled by tw), k[b,h,s,d], vt[b,h,d,s] (bf16). N=3072.
// EPI==1: out fp32 = acc + bias[n].  N=1024.
template <int EPI>
__global__ __launch_bounds__(256) void gemm_kernel(
    const unsigned short* __restrict__ A, const unsigned short* __restrict__ Bt,
    unsigned short* __restrict__ qo, unsigned short* __restrict__ ko, unsigned short* __restrict__ vto,
    float* __restrict__ outf, const float* __restrict__ bias, const float* __restrict__ tw) {
  __shared__ unsigned short As[128 * 64];   // 16 KB
  __shared__ unsigned short Bs[128 * 64];   // 16 KB

  int tid = threadIdx.x;
  int lane = tid & 63, wid = tid >> 6;
  int quad = lane >> 4, l16 = lane & 15;
  int wm = wid >> 1, wn = wid & 1;
  int m0 = blockIdx.y * 128, n0 = blockIdx.x * 128;

  // staging: instr c covers rows wid*32 + c*8 + lane/8; granule lane&7, global granule ^(row&7)
  const unsigned short* gA[4];
  const unsigned short* gB[4];
  unsigned short* lA[4];
  unsigned short* lB[4];
#pragma unroll
  for (int c = 0; c < 4; c++) {
    int row = wid * 32 + c * 8 + (lane >> 3);
    int gcol = ((lane & 7) ^ (row & 7)) * 8;
    gA[c] = A + (size_t)(m0 + row) * 1024 + gcol;
    gB[c] = Bt + (size_t)(n0 + row) * 1024 + gcol;
    lA[c] = &As[(wid * 32 + c * 8) * 64];
    lB[c] = &Bs[(wid * 32 + c * 8) * 64];
  }

  // frag reads: phys granule = (kk*4+quad) ^ (l16&7)  (row&7 == l16&7 for 16-aligned tiles)
  int aoff[2];
#pragma unroll
  for (int kk = 0; kk < 2; kk++) aoff[kk] = (((kk * 4 + quad) ^ (l16 & 7)) * 8);

  floatx4 acc[4][4];
#pragma unroll
  for (int mi = 0; mi < 4; mi++)
#pragma unroll
    for (int ni = 0; ni < 4; ni++)
#pragma unroll
      for (int r = 0; r < 4; r++) acc[mi][ni][r] = 0.f;

  for (int k0 = 0; k0 < 1024; k0 += 64) {
    __syncthreads();   // prior iteration's frag reads done in all waves
#pragma unroll
    for (int c = 0; c < 4; c++) {
      load16_lds(gA[c] + k0, lA[c]);
      load16_lds(gB[c] + k0, lB[c]);
    }
    asm volatile("s_waitcnt vmcnt(0) lgkmcnt(0)" ::: "memory");  // insurance: drain before barrier
    __syncthreads();   // staged data visible to all waves

#pragma unroll
    for (int kk = 0; kk < 2; kk++) {
      short8 a_frag[4], b_frag[4];
#pragma unroll
      for (int mi = 0; mi < 4; mi++)
        a_frag[mi] = *(const short8*)&As[(wm * 64 + mi * 16 + l16) * 64 + aoff[kk]];
#pragma unroll
      for (int ni = 0; ni < 4; ni++)
        b_frag[ni] = *(const short8*)&Bs[(wn * 64 + ni * 16 + l16) * 64 + aoff[kk]];
#pragma unroll
      for (int mi = 0; mi < 4; mi++)
#pragma unroll
        for (int ni = 0; ni < 4; ni++)
          acc[mi][ni] = __builtin_amdgcn_mfma_f32_16x16x32_bf16(a_frag[mi], b_frag[ni], acc[mi][ni], 0, 0, 0);
    }
  }

  // epilogue.  C[row=quad*4+r (M), col=l16 (N)] per 16x16 tile.
#pragma unroll
  for (int mi = 0; mi < 4; mi++)
#pragma unroll
    for (int ni = 0; ni < 4; ni++)
#pragma unroll
      for (int r = 0; r < 4; r++) {
        int m = m0 + wm * 64 + mi * 16 + quad * 4 + r;
        int n = n0 + wn * 64 + ni * 16 + l16;
        float val = acc[mi][ni][r];
        if (EPI == 0) {
          int b = m >> 11, s = m & 2047;
          int proj = n >> 10, rem = n & 1023, hh = rem >> 6, d = rem & 63;
          size_t bh = (size_t)(b * NH + hh);
          if (proj == 0)      qo[(bh * SEQ + s) * HD + d] = f2bf(val * tw[bh]);
          else if (proj == 1) ko[(bh * SEQ + s) * HD + d] = f2bf(val);
          else                vto[(bh * HD + d) * SEQ + s] = f2bf(val);
        } else {
          outf[(size_t)m * EMB + n] = val + bias[n];
        }
      }
}

// ---------------- flash attention (no-max softmax; S and O both computed transposed) ----------------
// per (qtile, h, b); 128 Q rows / block, 4 waves x 32 qrows; 64-key K-tiles (32 iters).
// S^T = K·Q^T: C row = key (quad*4+r), col = qrow (l16)  ->  a lane owns 4 consecutive keys
// of one qrow, so the P^T transpose store is a packed ds_write_b64, and lsum is a per-lane
// scalar (qrow = l16).  O^T = (V^T)(P^T): epilogue lane holds fixed qrow + 4 consecutive d.
__global__ __launch_bounds__(256, 4) void attn_kernel(
    const unsigned short* __restrict__ qg, const unsigned short* __restrict__ kg,
    const unsigned short* __restrict__ vtg, unsigned short* __restrict__ aog) {
  __shared__ unsigned short Ks[64 * 64];    // 8 KB; [key][d], granule swizzle g^=(row&7)
  __shared__ unsigned short Vs[64 * 64];    // 8 KB; [d][key], granule swizzle g^=(row&7)
  __shared__ unsigned short Ps[4 * 2048];   // 16 KB; per-wave P^T 32 qrows x 64 keys,
                                            //   4-key chunk swizzle c^=(qrow&14)
  // total 32768 B -> LDS allows 5 blocks/CU; grid 1024 = 4/CU co-resident, no tail

  int tid = threadIdx.x;
  int lane = tid & 63, wid = tid >> 6;
  int quad = lane >> 4, l16 = lane & 15, l7 = lane & 7;
  int qt = blockIdx.x, h = blockIdx.y, b = blockIdx.z;
  int bh = b * NH + h;
  const unsigned short* qbase = qg + (size_t)bh * SEQ * HD + (size_t)qt * 128 * HD;
  const unsigned short* kbase = kg + (size_t)bh * SEQ * HD;
  const unsigned short* vbase = vtg + (size_t)bh * HD * SEQ;

  // Q B-fragments straight from global (one-time): B[n=qrow=l16][k=d=quad*8+j]
  short8 b_q[2][2];
#pragma unroll
  for (int mi = 0; mi < 2; mi++)
#pragma unroll
    for (int kk = 0; kk < 2; kk++)
      b_q[mi][kk] = *(const short8*)&qbase[(wid * 32 + mi * 16 + l16) * 64 + kk * 32 + quad * 8];

  // staging: instr c covers rows wid*16 + c*8 + lane/8, granule lane&7 ^ row&7
  const unsigned short* gK[2];
  const unsigned short* gV[2];
  unsigned short* lK[2];
  unsigned short* lV[2];
#pragma unroll
  for (int c = 0; c < 2; c++) {
    int row = wid * 16 + c * 8 + (lane >> 3);
    int gcol = ((lane & 7) ^ (row & 7)) * 8;
    gK[c] = kbase + row * 64 + gcol;            // + kb*4096 per iter
    gV[c] = vbase + (size_t)row * SEQ + gcol;   // + kb*64  per iter
    lK[c] = &Ks[(wid * 16 + c * 8) * 64];
    lV[c] = &Vs[(wid * 16 + c * 8) * 64];
  }

  // K/V frag reads: row base l16*64, phys granule (i*4+quad)^l7
  int pg[2];
#pragma unroll
  for (int i = 0; i < 2; i++) pg[i] = l16 * 64 + (((i * 4 + quad) ^ l7) * 8);

  // P^T addressing (shorts). wave base + row l16 (+ mi*16 rows = mi*1024 shorts)
  int wbase = wid * 2048;
  int chunkx = l16 & 14;
  int pwa[4];   // write: chunk (ni*4+quad) ^ chunkx
#pragma unroll
  for (int ni = 0; ni < 4; ni++)
    pwa[ni] = wbase + l16 * 64 + (((ni * 4 + quad) ^ chunkx) * 4);
  int pra[2];   // read: chunk pair (kk2*8+quad*2) ^ chunkx
#pragma unroll
  for (int kk2 = 0; kk2 < 2; kk2++)
    pra[kk2] = wbase + l16 * 64 + (((kk2 * 8 + quad * 2) ^ chunkx) * 4);

  floatx4 O[4][2];   // [di][mi]  (O^T: row=d, col=qrow)
  float lsum[2] = {0.f, 0.f};
#pragma unroll
  for (int di = 0; di < 4; di++)
#pragma unroll
    for (int mi = 0; mi < 2; mi++)
#pragma unroll
      for (int r = 0; r < 4; r++) O[di][mi][r] = 0.f;

  for (int kb = 0; kb < 32; kb++) {
    __syncthreads();   // all waves' prior-iter LDS reads done
#pragma unroll
    for (int c = 0; c < 2; c++) {
      load16_lds(gK[c] + kb * 4096, lK[c]);
      load16_lds(gV[c] + kb * 64, lV[c]);
    }
    asm volatile("s_waitcnt vmcnt(0) lgkmcnt(0)" ::: "memory");  // insurance: drain before barrier
    __syncthreads();   // staged tiles visible

    // S^T = K @ Q^T : 64 keys (4 m-tiles) x 32 qrows (2 n-tiles)
    floatx4 st[4][2];
#pragma unroll
    for (int ni = 0; ni < 4; ni++)
#pragma unroll
      for (int mi = 0; mi < 2; mi++)
#pragma unroll
        for (int r = 0; r < 4; r++) st[ni][mi][r] = 0.f;
#pragma unroll
    for (int kk = 0; kk < 2; kk++)
#pragma unroll
      for (int ni = 0; ni < 4; ni++) {
        short8 a_k = *(const short8*)&Ks[ni * 1024 + pg[kk]];
#pragma unroll
        for (int mi = 0; mi < 2; mi++)
          st[ni][mi] = __builtin_amdgcn_mfma_f32_16x16x32_bf16(a_k, b_q[mi][kk], st[ni][mi], 0, 0, 0);
      }

    // P = exp2(S) (|S| <~ 10, no max needed); pack 4 keys -> one b64 write to P^T
#pragma unroll
    for (int mi = 0; mi < 2; mi++)
#pragma unroll
      for (int ni = 0; ni < 4; ni++) {
        float p0 = __builtin_amdgcn_exp2f(st[ni][mi][0]);
        float p1 = __builtin_amdgcn_exp2f(st[ni][mi][1]);
        float p2 = __builtin_amdgcn_exp2f(st[ni][mi][2]);
        float p3 = __builtin_amdgcn_exp2f(st[ni][mi][3]);
        lsum[mi] += (p0 + p1) + (p2 + p3);
        unsigned int u0 = __float_as_uint(p0) + 0x8000u, u1 = __float_as_uint(p1) + 0x8000u;
        unsigned int u2 = __float_as_uint(p2) + 0x8000u, u3 = __float_as_uint(p3) + 0x8000u;
        uint2 w;
        w.x = (u0 >> 16) | (u1 & 0xffff0000u);
        w.y = (u2 >> 16) | (u3 & 0xffff0000u);
        *(uint2*)&Ps[pwa[ni] + mi * 1024] = w;
      }
    asm volatile("s_waitcnt lgkmcnt(0)" ::: "memory");  // insurance: P writes land before reads

    // O^T += (V^T)(P^T):  A = V^T frag (m=d, k=key), B = P^T frag (n=qrow, k=key)
#pragma unroll
    for (int kk2 = 0; kk2 < 2; kk2++) {
      short8 av[4], bp[2];
#pragma unroll
      for (int di = 0; di < 4; di++)
        av[di] = *(const short8*)&Vs[di * 1024 + pg[kk2]];
#pragma unroll
      for (int mi = 0; mi < 2; mi++)
        bp[mi] = *(const short8*)&Ps[pra[kk2] + mi * 1024];
#pragma unroll
      for (int di = 0; di < 4; di++)
#pragma unroll
        for (int mi = 0; mi < 2; mi++)
          O[di][mi] = __builtin_amdgcn_mfma_f32_16x16x32_bf16(av[di], bp[mi], O[di][mi], 0, 0, 0);
    }
  }

  // lsum: lanes sharing qrow are {l16, l16+16, l16+32, l16+48} -> 2 shuffles
  float inv[2];
#pragma unroll
  for (int mi = 0; mi < 2; mi++) {
    lsum[mi] += __shfl_xor(lsum[mi], 16);
    lsum[mi] += __shfl_xor(lsum[mi], 32);
    inv[mi] = 1.0f / lsum[mi];
  }

  // epilogue: lane holds qrow = mi*16+l16, d = di*16+quad*4+r -> 4 packed bf16 per store
#pragma unroll
  for (int mi = 0; mi < 2; mi++) {
    int s = qt * 128 + wid * 32 + mi * 16 + l16;
    size_t rowbase = ((size_t)(b * SEQ + s) * NH + h) * HD;
#pragma unroll
    for (int di = 0; di < 4; di++) {
      unsigned int u0 = __float_as_uint(O[di][mi][0] * inv[mi]) + 0x8000u;
      unsigned int u1 = __float_as_uint(O[di][mi][1] * inv[mi]) + 0x8000u;
      unsigned int u2 = __float_as_uint(O[di][mi][2] * inv[mi]) + 0x8000u;
      unsigned int u3 = __float_as_uint(O[di][mi][3] * inv[mi]) + 0x8000u;
      uint2 w;
      w.x = (u0 >> 16) | (u1 & 0xffff0000u);
      w.y = (u2 >> 16) | (u3 & 0xffff0000u);
      *(uint2*)&aog[rowbase + di * 16 + quad * 4] = w;
    }
  }
}

// ---------------- launch ----------------
// Workspace budget: r4 carved 72 MiB of d_ws; if ws_size < that, the tail carve scribbles
// over neighboring allocations (pristine input copies) -> persistent post-replay divergence
// (exactly the r4 failure signature). Fix: q/k tensors live in d_out (32 MB, dead before
// gemm<1> overwrites it); ws now carves only ~40 MiB.
extern "C" void kernel_launch(void* const* d_in, const int* in_sizes, int n_in,
                              void* d_out, int out_size, void* d_ws, size_t ws_size,
                              hipStream_t stream) {
  (void)in_sizes; (void)n_in; (void)out_size; (void)ws_size;
  const float* x  = (const float*)d_in[0];
  const float* te = (const float*)d_in[1];
  const float* Wq = (const float*)d_in[2];
  const float* Wk = (const float*)d_in[3];
  const float* Wv = (const float*)d_in[4];
  const float* Wo = (const float*)d_in[5];
  const float* bo = (const float*)d_in[6];
  const float* Wt = (const float*)d_in[7];
  const float* bt = (const float*)d_in[8];
  float* out = (float*)d_out;

  char* ws = (char*)d_ws;
  size_t off = 0;
  auto carve = [&](size_t bytes) -> void* {
    void* p = ws + off;
    off += (bytes + 255) & ~(size_t)255;
    return p;
  };
  float* twb            = (float*)carve(64 * sizeof(float));
  unsigned short* xb    = (unsigned short*)carve((size_t)MROWS * EMB * 2);   // 16 MB
  unsigned short* wqkvt = (unsigned short*)carve((size_t)3 * EMB * EMB * 2); //  6 MB
  unsigned short* wot   = (unsigned short*)carve((size_t)EMB * EMB * 2);     //  2 MB
  unsigned short* vtb   = (unsigned short*)carve((size_t)MROWS * EMB * 2);   // 16 MB
  // q/k live in d_out (8192*1024 fp32 = 32 MB = 2 * 16 MB bf16); both are dead before
  // gemm<1> overwrites d_out with the final result.
  unsigned short* qb    = (unsigned short*)d_out;
  unsigned short* kb    = (unsigned short*)d_out + (size_t)MROWS * EMB;
  unsigned short* ao    = xb;  // alias: xb is dead after GEMM0

  time_weights_kernel<<<dim3(1), dim3(64), 0, stream>>>(te, Wt, bt, twb);
  convert_x_kernel<<<dim3(8192), dim3(256), 0, stream>>>((const float4*)x, xb);
  transpose_convert4_kernel<<<dim3(32, 32, 4), dim3(32, 8), 0, stream>>>(Wq, Wk, Wv, Wo, wqkvt, wot);
  gemm_kernel<0><<<dim3(24, 64), dim3(256), 0, stream>>>(xb, wqkvt, qb, kb, vtb, nullptr, nullptr, twb);
  attn_kernel<<<dim3(16, NH, NB), dim3(256), 0, stream>>>(qb, kb, vtb, ao);
  gemm_kernel<1><<<dim3(8, 64), dim3(256), 0, stream>>>(ao, wot, nullptr, nullptr, nullptr, out, bo, nullptr);
}